// Round 3
// baseline (20.110 us; speedup 1.0000x reference)
//
#include <hip/hip_runtime.h>

#define VOCAB 1024
#define ARCS  16
#define MAX_ORDER 4
#define CHAIN (MAX_ORDER - 1)
#define START_STATE 0
#define WAVE 64

// One wave (64 threads) per hypothesis. Zero LDS -> 32 waves/CU.
// Priority (highest-order state wins) resolved IN REGISTERS via readlane
// dedup; overlay applied as a fenced global scatter after the dense stores.
__global__ __launch_bounds__(WAVE, 8) void ngram_advance_kernel(
    const float* __restrict__ arcs_weights,
    const float* __restrict__ backoff_weights,
    const int*   __restrict__ ilabels,
    const int*   __restrict__ to_states,
    const int*   __restrict__ backoff_to,
    const int*   __restrict__ state_start,
    const int*   __restrict__ state_end,
    const int*   __restrict__ states,
    float*       __restrict__ out_scores,   // [B, V]
    float*       __restrict__ out_next)     // [B, V] state ids as f32
{
    const int tid = threadIdx.x;
    const int b   = blockIdx.x;

    // ---- Chain walk: wave-uniform (compiler scalarizes to s_load). ----
    int   cur = states[b];
    float acc = 0.0f;
    const int   cs0 = cur;  const float ca0 = acc;
    if (cur != START_STATE) { acc += backoff_weights[cur]; cur = backoff_to[cur]; }
    const int   cs1 = cur;  const float ca1 = acc;
    if (cur != START_STATE) { acc += backoff_weights[cur]; cur = backoff_to[cur]; }
    const int   cs2 = cur;  const float ca2 = acc;
    if (cur != START_STATE) { acc += backoff_weights[cur]; }
    const float accf = acc;

    // ---- Parallel arc fetch: lanes 0..47, level = tid>>4, arc = tid&15 ----
    const int level = tid >> 4;
    const int arc   = tid & (ARCS - 1);
    int   lab = -1, ns = 0;
    float sc  = 0.0f;
    bool  ok  = false;
    if (tid < CHAIN * ARCS) {
        const int   s    = (level == 0) ? cs0 : ((level == 1) ? cs1 : cs2);
        const float cacc = (level == 0) ? ca0 : ((level == 1) ? ca1 : ca2);
        if (s != START_STATE) {
            const int idx = state_start[s] + arc;
            if (idx < state_end[s]) {
                lab = ilabels[idx];
                sc  = cacc + arcs_weights[idx];
                ns  = to_states[idx];
                ok  = true;
            }
        }
    }

    // ---- In-register dedup: a lane is killed if a LOWER level (higher
    // n-gram order, higher priority) has a valid arc with the same label.
    // Reference semantics: found = union of valid labels of earlier levels.
    // Invalid lanes hold lab = -1, which never matches a real label.
    int kill = 0;
    #pragma unroll
    for (int k = 0; k < 2 * ARCS; ++k) {
        const int lk = __builtin_amdgcn_readlane(lab, k);
        if (k < ARCS) kill |= (int)(level >= 1) & (int)(lab == lk);
        else          kill |= (int)(level == 2) & (int)(lab == lk);
    }
    const bool do_scatter = ok && !kill;   // survivors: pairwise-distinct labels

    // ---- Dense fill straight to global (start-state table is L1-hot). ----
    float* __restrict__ so = out_scores + (size_t)b * VOCAB;
    float* __restrict__ no = out_next   + (size_t)b * VOCAB;
    #pragma unroll
    for (int i = 0; i < VOCAB / (WAVE * 4); ++i) {
        const int v = (tid + i * WAVE) * 4;
        const float4 dw = *(const float4*)&arcs_weights[v];
        const int4   dn = *(const int4*)&to_states[v];
        float4 rs, rn;
        rs.x = accf + dw.x;  rs.y = accf + dw.y;
        rs.z = accf + dw.z;  rs.w = accf + dw.w;
        rn.x = (float)dn.x;  rn.y = (float)dn.y;
        rn.z = (float)dn.z;  rn.w = (float)dn.w;
        *(float4*)&so[v] = rs;
        *(float4*)&no[v] = rn;
    }

    // ---- Fence: dense stores must reach the L2 coherency point before the
    // overlay scatter so the scatter wins the same-address race. ----
    asm volatile("s_waitcnt vmcnt(0)" ::: "memory");

    if (do_scatter) {
        so[lab] = sc;
        no[lab] = (float)ns;
    }
}

extern "C" void kernel_launch(void* const* d_in, const int* in_sizes, int n_in,
                              void* d_out, int out_size, void* d_ws, size_t ws_size,
                              hipStream_t stream) {
    const float* arcs_weights    = (const float*)d_in[0];
    const float* backoff_weights = (const float*)d_in[1];
    const int*   ilabels         = (const int*)d_in[2];
    const int*   to_states       = (const int*)d_in[3];
    const int*   backoff_to      = (const int*)d_in[4];
    const int*   state_start     = (const int*)d_in[5];
    const int*   state_end       = (const int*)d_in[6];
    const int*   states          = (const int*)d_in[7];

    const int B = in_sizes[7];                           // 8192 hypotheses
    float* out_scores = (float*)d_out;                   // first B*V floats
    float* out_next   = out_scores + (size_t)B * VOCAB;  // second B*V

    ngram_advance_kernel<<<B, WAVE, 0, stream>>>(
        arcs_weights, backoff_weights, ilabels, to_states, backoff_to,
        state_start, state_end, states, out_scores, out_next);
}